// Round 1
// baseline (1135.531 us; speedup 1.0000x reference)
//
#include <hip/hip_runtime.h>
#include <math.h>

typedef _Float16 f16;
typedef _Float16 f16x4 __attribute__((ext_vector_type(4)));
typedef _Float16 f16x8 __attribute__((ext_vector_type(8)));
typedef float f32x4 __attribute__((ext_vector_type(4)));

#define NTOK 98
#define BWIN 2048

// ---------------- workspace layout (bytes) ----------------
#define OFF_BT    0u                      // 507*8*4
#define OFF_RPB   (1u<<20)                // 8*98*98*4
#define OFF_WQKV  (2u<<20)                // 768*256*2
#define OFF_WPROJ (3u<<20)                // 256*256*2
#define OFF_Q     (4u<<20)
#define QKV_SZ    (2048u*8u*98u*32u*2u)   // 102,760,448
#define OFF_K     (OFF_Q + QKV_SZ)
#define OFF_V     (OFF_K + QKV_SZ)
#define OFF_AV    (OFF_V + QKV_SZ)        // av: 2048*98*256*2

// ---------------- prep: cpb MLP -> bt[507][8] ----------------
__global__ void prep_bt(const float* __restrict__ w1, const float* __restrict__ b1,
                        const float* __restrict__ w2, float* __restrict__ bt) {
  int t = blockIdx.x;            // 0..506
  int lane = threadIdx.x;        // 64
  int a = t / 169, rem = t % 169, b = rem / 13, c = rem % 13;
  float g0 = ((float)(a - 1) / 1.000001f) * 8.0f;
  float g1 = ((float)(b - 6) / 6.000001f) * 8.0f;
  float g2 = ((float)(c - 6) / 6.000001f) * 8.0f;
  float t0 = log2f(fabsf(g0) + 1.0f) / 3.0f; t0 = (g0 < 0.f) ? -t0 : t0;
  float t1 = log2f(fabsf(g1) + 1.0f) / 3.0f; t1 = (g1 < 0.f) ? -t1 : t1;
  float t2 = log2f(fabsf(g2) + 1.0f) / 3.0f; t2 = (g2 < 0.f) ? -t2 : t2;
  float part[8] = {0.f,0.f,0.f,0.f,0.f,0.f,0.f,0.f};
#pragma unroll
  for (int jj = 0; jj < 8; jj++) {
    int j = lane * 8 + jj;
    float hv = t0 * w1[j*3] + t1 * w1[j*3+1] + t2 * w1[j*3+2] + b1[j];
    hv = fmaxf(hv, 0.f);
#pragma unroll
    for (int h = 0; h < 8; h++) part[h] += hv * w2[h*512 + j];
  }
#pragma unroll
  for (int m = 1; m < 64; m <<= 1)
#pragma unroll
    for (int h = 0; h < 8; h++) part[h] += __shfl_xor(part[h], m);
  if (lane == 0)
#pragma unroll
    for (int h = 0; h < 8; h++) bt[t*8 + h] = part[h];
}

// ---------------- prep: gather + sigmoid -> rpb[8][98][98] fp32 ----------------
__global__ void prep_rpb(const float* __restrict__ bt, float* __restrict__ rpb) {
  int bid = blockIdx.x;          // 8*98
  int h = bid / 98, i = bid % 98;
  int j = threadIdx.x;
  if (j >= 98) return;
  int di = i / 49, hi = (i % 49) / 7, wi = i % 7;
  int dj = j / 49, hj = (j % 49) / 7, wj = j % 7;
  int idx = (di - dj + 1) * 169 + (hi - hj + 6) * 13 + (wi - wj + 6);
  float v = bt[idx*8 + h];
  rpb[(h*98 + i)*98 + j] = 16.0f / (1.0f + expf(-v));
}

// ---------------- prep: weights fp32 -> fp16 ----------------
__global__ void prep_wt(const float* __restrict__ qkv_w, const float* __restrict__ proj_w,
                        f16* __restrict__ wq, f16* __restrict__ wp) {
  int t = blockIdx.x * 256 + threadIdx.x;   // grid covers 768*256
  wq[t] = (f16)qkv_w[t];
  if (t < 256*256) wp[t] = (f16)proj_w[t];
}

// ---------------- QKV GEMM: fused fp32->f16 A, reg-double-buffer prefetch ----------------
// x:[200704,256] fp32, wq:[768,256] f16 -> q/k/v scatter [b][h][tok][32] f16
#define ASTR 40
__global__ __launch_bounds__(256) void qkv_gemm(
    const float* __restrict__ x, const f16* __restrict__ wq,
    const float* __restrict__ q_bias, const float* __restrict__ v_bias,
    f16* __restrict__ qw, f16* __restrict__ kw, f16* __restrict__ vw) {
  __shared__ f16 Al[128*ASTR];
  __shared__ f16 Bl[128*ASTR];
  int tid = threadIdx.x;
  int w = tid >> 6, lane = tid & 63, q4 = lane >> 4, l15 = lane & 15;

  // XCD-chunked bijective swizzle (nwg = 9408 = 8*1176), then n-tile FASTEST:
  // the 6 blocks sharing an A panel run adjacently on one XCD -> A fetched once.
  int bid = blockIdx.x;
  int sid = (bid & 7) * 1176 + (bid >> 3);
  int n_t = sid % 6, m_t = sid / 6;
  int m0 = m_t * 128, n0 = n_t * 128;

  // precomputed global/LDS staging addresses
  const float* ga[4]; f16* la[4];
#pragma unroll
  for (int p = 0; p < 4; p++) {
    int c = tid + p*256, r = c >> 3, k4 = c & 7;     // 128 rows x 8 chunks of 4 fp32
    ga[p] = x + (size_t)(m0 + r)*256 + k4*4;
    la[p] = &Al[r*ASTR + k4*4];
  }
  const f16* gb[2]; f16* lb[2];
#pragma unroll
  for (int p = 0; p < 2; p++) {
    int c = tid + p*256, r = c >> 2, kc = c & 3;     // 128 rows x 4 chunks of 8 f16
    gb[p] = wq + (size_t)(n0 + r)*256 + kc*8;
    lb[p] = &Bl[r*ASTR + kc*8];
  }

  f32x4 acc[2][8] = {};
  float4 aP[4], aQ[4]; uint4 bP[2], bQ[2];
#pragma unroll
  for (int p = 0; p < 4; p++) aP[p] = *(const float4*)(ga[p]);
#pragma unroll
  for (int p = 0; p < 2; p++) bP[p] = *(const uint4*)(gb[p]);

#define GSTEP(CA, CB, NA, NB, KS, PF)                                          \
  {                                                                            \
    if (PF) {                                                                  \
      _Pragma("unroll")                                                        \
      for (int p = 0; p < 4; p++) NA[p] = *(const float4*)(ga[p] + ((KS)+1)*32); \
      _Pragma("unroll")                                                        \
      for (int p = 0; p < 2; p++) NB[p] = *(const uint4*)(gb[p] + ((KS)+1)*32);  \
    }                                                                          \
    __syncthreads();                                                           \
    _Pragma("unroll")                                                          \
    for (int p = 0; p < 4; p++) {                                              \
      f16x4 cv;                                                                \
      cv[0]=(f16)CA[p].x; cv[1]=(f16)CA[p].y;                                  \
      cv[2]=(f16)CA[p].z; cv[3]=(f16)CA[p].w;                                  \
      *(f16x4*)(la[p]) = cv;                                                   \
    }                                                                          \
    _Pragma("unroll")                                                          \
    for (int p = 0; p < 2; p++) *(uint4*)(lb[p]) = CB[p];                      \
    __syncthreads();                                                           \
    f16x8 af[2], bf[8];                                                        \
    _Pragma("unroll")                                                          \
    for (int mt = 0; mt < 2; mt++)                                             \
      af[mt] = *(const f16x8*)(&Al[(w*32 + mt*16 + l15)*ASTR + q4*8]);         \
    _Pragma("unroll")                                                          \
    for (int nt = 0; nt < 8; nt++)                                             \
      bf[nt] = *(const f16x8*)(&Bl[(nt*16 + l15)*ASTR + q4*8]);                \
    _Pragma("unroll")                                                          \
    for (int mt = 0; mt < 2; mt++)                                             \
      _Pragma("unroll")                                                        \
      for (int nt = 0; nt < 8; nt++)                                           \
        acc[mt][nt] = __builtin_amdgcn_mfma_f32_16x16x32_f16(af[mt], bf[nt], acc[mt][nt], 0, 0, 0); \
  }

  for (int ks2 = 0; ks2 < 8; ks2 += 2) {
    GSTEP(aP, bP, aQ, bQ, ks2, 1)
    GSTEP(aQ, bQ, aP, bP, (ks2+1), (ks2 < 6))
  }
#undef GSTEP

  // epilogue: +bias, scatter to q/k/v [b][h][tok][d] fp16. s uniform per block.
  int s = n_t >> 1;
  f16* dst = (s == 0) ? qw : ((s == 1) ? kw : vw);
#pragma unroll
  for (int mt = 0; mt < 2; mt++)
#pragma unroll
    for (int nt = 0; nt < 8; nt++) {
      int c = n0 + nt*16 + l15;
      int hcol = (c >> 5) & 7, d = c & 31;
      float bias = (s == 0) ? q_bias[c & 255] : ((s == 2) ? v_bias[c & 255] : 0.0f);
#pragma unroll
      for (int r = 0; r < 4; r++) {
        int m = m0 + w*32 + mt*16 + q4*4 + r;
        int b = m / 98, tok = m % 98;
        dst[((size_t)(b*8 + hcol)*98 + tok)*32 + d] = (f16)(acc[mt][nt][r] + bias);
      }
    }
}

// ---------------- attention: ONE WAVE per (window, head), no barriers/atomics ----------------
#define P_STR 136
__global__ __launch_bounds__(256) void attn_kernel(
    const f16* __restrict__ qw, const f16* __restrict__ kw, const f16* __restrict__ vw,
    const float* __restrict__ rpb, const float* __restrict__ logit_scale,
    f16* __restrict__ av) {
  __shared__ f16 Ps[4*16*P_STR];   // per-wave 16x136 P bounce (C-layout -> A-layout)

  int tid = threadIdx.x;
  int wv = tid >> 6, lane = tid & 63, q4 = lane >> 4, l15 = lane & 15;
  int pair = blockIdx.x * 4 + wv;
  int b = pair >> 3, h = pair & 7;
  float scale = __expf(fminf(logit_scale[h], 4.6051701859880914f));
  const f16* qg = qw + ((size_t)pair) * (98*32);
  const f16* kg = kw + ((size_t)pair) * (98*32);
  const f16* vg = vw + ((size_t)pair) * (98*32);
  f16* pbuf = &Ps[wv * 16 * P_STR];

  // zero P cols [112,128) once (never rewritten)
  {
    int r = lane >> 2, c0 = 112 + (lane & 3) * 4;
    *(ushort4*)(&pbuf[r*P_STR + c0]) = ushort4{0,0,0,0};
  }

  // ---- K fragments, L2-normalized, resident in regs ----
  f16x8 kf[7];
#pragma unroll
  for (int nt = 0; nt < 7; nt++) {
    int row = nt*16 + l15; if (row > 97) row = 97;
    f16x8 raw = *(const f16x8*)(kg + row*32 + q4*8);
    float ss = 0.f;
#pragma unroll
    for (int j = 0; j < 8; j++) { float v = (float)raw[j]; ss = fmaf(v, v, ss); }
    ss += __shfl_xor(ss, 16);
    ss += __shfl_xor(ss, 32);
    float inv = 1.0f / fmaxf(sqrtf(ss), 1e-12f);
#pragma unroll
    for (int j = 0; j < 8; j++) kf[nt][j] = (f16)((float)raw[j] * inv);
  }

  // ---- V fragments: B-layout (needs V^T) via scalar loads, resident ----
  f16x8 vf[2][4];
#pragma unroll
  for (int n = 0; n < 2; n++)
#pragma unroll
    for (int kt = 0; kt < 4; kt++)
#pragma unroll
      for (int j = 0; j < 8; j++) {
        int tok = kt*32 + q4*8 + j; if (tok > 97) tok = 97;
        vf[n][kt][j] = vg[tok*32 + n*16 + l15];
      }

  const float* rpb_h = rpb + (size_t)h * 98 * 98;

  // ---- 7 row strips of 16 ----
  for (int mt = 0; mt < 7; mt++) {
    // Q strip fragment, normalized
    int qrow = mt*16 + l15; if (qrow > 97) qrow = 97;
    f16x8 qraw = *(const f16x8*)(qg + qrow*32 + q4*8);
    float ss = 0.f;
#pragma unroll
    for (int j = 0; j < 8; j++) { float v = (float)qraw[j]; ss = fmaf(v, v, ss); }
    ss += __shfl_xor(ss, 16);
    ss += __shfl_xor(ss, 32);
    float qinv = 1.0f / fmaxf(sqrtf(ss), 1e-12f);
    f16x8 aq;
#pragma unroll
    for (int j = 0; j < 8; j++) aq[j] = (f16)((float)qraw[j] * qinv);

    // S tiles -> logits
    f32x4 lg[7];
#pragma unroll
    for (int nt = 0; nt < 7; nt++) {
      f32x4 z = {0.f,0.f,0.f,0.f};
      lg[nt] = __builtin_amdgcn_mfma_f32_16x16x32_f16(aq, kf[nt], z, 0, 0, 0);
    }
#pragma unroll
    for (int nt = 0; nt < 7; nt++) {
      int col = nt*16 + l15;
#pragma unroll
      for (int r = 0; r < 4; r++) {
        int row = mt*16 + q4*4 + r;
        float lv = -1e30f;
        if (row < 98 && col < 98)
          lv = fmaf(scale, lg[nt][r], rpb_h[row*98 + col]);
        lg[nt][r] = lv;
      }
    }
    // row max (7 fmax + 4 shfls per r)
    float mx[4];
#pragma unroll
    for (int r = 0; r < 4; r++) {
      float m = lg[0][r];
#pragma unroll
      for (int nt = 1; nt < 7; nt++) m = fmaxf(m, lg[nt][r]);
      m = fmaxf(m, __shfl_xor(m, 1));
      m = fmaxf(m, __shfl_xor(m, 2));
      m = fmaxf(m, __shfl_xor(m, 4));
      m = fmaxf(m, __shfl_xor(m, 8));
      mx[r] = m;
    }
    // exp, row sum, write P strip (cols 98..111 become exp(-inf)=0)
    float rs[4] = {0.f,0.f,0.f,0.f};
#pragma unroll
    for (int nt = 0; nt < 7; nt++) {
      int col = nt*16 + l15;
#pragma unroll
      for (int r = 0; r < 4; r++) {
        float p = __expf(lg[nt][r] - mx[r]);
        rs[r] += p;
        pbuf[(q4*4 + r)*P_STR + col] = (f16)p;
      }
    }
    float inv[4];
#pragma unroll
    for (int r = 0; r < 4; r++) {
      float s = rs[r];
      s += __shfl_xor(s, 1);
      s += __shfl_xor(s, 2);
      s += __shfl_xor(s, 4);
      s += __shfl_xor(s, 8);
      inv[r] = 1.0f / s;
    }
    // P C-layout -> A-layout via wave-private LDS (in-order DS, no barrier)
    f16x8 pf[4];
#pragma unroll
    for (int kt = 0; kt < 4; kt++)
      pf[kt] = *(const f16x8*)(&pbuf[l15*P_STR + kt*32 + q4*8]);
    // AV
#pragma unroll
    for (int n = 0; n < 2; n++) {
      f32x4 acc = {0.f,0.f,0.f,0.f};
#pragma unroll
      for (int kt = 0; kt < 4; kt++)
        acc = __builtin_amdgcn_mfma_f32_16x16x32_f16(pf[kt], vf[n][kt], acc, 0, 0, 0);
      int d = n*16 + l15;
#pragma unroll
      for (int r = 0; r < 4; r++) {
        int row = mt*16 + q4*4 + r;
        if (row < 98)
          av[((size_t)(b*98 + row))*256 + h*32 + d] = (f16)(acc[r] * inv[r]);
      }
    }
  }
}

// ---------------- proj GEMM: [200704,256](f16) x [256,256] + bias -> fp32 out ----------------
__global__ __launch_bounds__(256) void proj_gemm(
    const f16* __restrict__ avi, const f16* __restrict__ wp,
    const float* __restrict__ pb, float* __restrict__ out) {
  __shared__ f16 Al[128*ASTR];
  __shared__ f16 Bl[128*ASTR];
  int tid = threadIdx.x;
  int w = tid >> 6, lane = tid & 63, q4 = lane >> 4, l15 = lane & 15;

  // XCD-chunked bijective swizzle (nwg = 3136 = 8*392), n-tile fastest
  int bid = blockIdx.x;
  int sid = (bid & 7) * 392 + (bid >> 3);
  int n_t = sid & 1, m_t = sid >> 1;
  int m0 = m_t * 128, n0 = n_t * 128;

  const f16* ga[2]; f16* la[2];
  const f16* gb[2]; f16* lb[2];
#pragma unroll
  for (int p = 0; p < 2; p++) {
    int c = tid + p*256, r = c >> 2, kc = c & 3;
    ga[p] = avi + (size_t)(m0 + r)*256 + kc*8;
    la[p] = &Al[r*ASTR + kc*8];
    gb[p] = wp + (size_t)(n0 + r)*256 + kc*8;
    lb[p] = &Bl[r*ASTR + kc*8];
  }

  f32x4 acc[2][8] = {};
  uint4 aP[2], aQ[2], bP[2], bQ[2];
#pragma unroll
  for (int p = 0; p < 2; p++) { aP[p] = *(const uint4*)(ga[p]); bP[p] = *(const uint4*)(gb[p]); }

#define PSTEP(CA, CB, NA, NB, KS, PF)                                          \
  {                                                                            \
    if (PF) {                                                                  \
      _Pragma("unroll")                                                        \
      for (int p = 0; p < 2; p++) {                                            \
        NA[p] = *(const uint4*)(ga[p] + ((KS)+1)*32);                          \
        NB[p] = *(const uint4*)(gb[p] + ((KS)+1)*32);                          \
      }                                                                        \
    }                                                                          \
    __syncthreads();                                                           \
    _Pragma("unroll")                                                          \
    for (int p = 0; p < 2; p++) {                                              \
      *(uint4*)(la[p]) = CA[p];                                                \
      *(uint4*)(lb[p]) = CB[p];                                                \
    }                                                                          \
    __syncthreads();                                                           \
    f16x8 af[2], bf[8];                                                        \
    _Pragma("unroll")                                                          \
    for (int mt = 0; mt < 2; mt++)                                             \
      af[mt] = *(const f16x8*)(&Al[(w*32 + mt*16 + l15)*ASTR + q4*8]);         \
    _Pragma("unroll")                                                          \
    for (int nt = 0; nt < 8; nt++)                                             \
      bf[nt] = *(const f16x8*)(&Bl[(nt*16 + l15)*ASTR + q4*8]);                \
    _Pragma("unroll")                                                          \
    for (int mt = 0; mt < 2; mt++)                                             \
      _Pragma("unroll")                                                        \
      for (int nt = 0; nt < 8; nt++)                                           \
        acc[mt][nt] = __builtin_amdgcn_mfma_f32_16x16x32_f16(af[mt], bf[nt], acc[mt][nt], 0, 0, 0); \
  }

  for (int ks2 = 0; ks2 < 8; ks2 += 2) {
    PSTEP(aP, bP, aQ, bQ, ks2, 1)
    PSTEP(aQ, bQ, aP, bP, (ks2+1), (ks2 < 6))
  }
#undef PSTEP

#pragma unroll
  for (int mt = 0; mt < 2; mt++)
#pragma unroll
    for (int nt = 0; nt < 8; nt++) {
      int c = n0 + nt*16 + l15;
      float bias = pb[c];
#pragma unroll
      for (int r = 0; r < 4; r++) {
        int m = m0 + w*32 + mt*16 + q4*4 + r;
        out[(size_t)m*256 + c] = acc[mt][nt][r] + bias;
      }
    }
}

extern "C" void kernel_launch(void* const* d_in, const int* in_sizes, int n_in,
                              void* d_out, int out_size, void* d_ws, size_t ws_size,
                              hipStream_t stream) {
  const float* x           = (const float*)d_in[0];
  const float* qkv_w       = (const float*)d_in[1];
  const float* q_bias      = (const float*)d_in[2];
  const float* v_bias      = (const float*)d_in[3];
  const float* logit_scale = (const float*)d_in[4];
  const float* cpb_w1      = (const float*)d_in[5];
  const float* cpb_b1      = (const float*)d_in[6];
  const float* cpb_w2      = (const float*)d_in[7];
  const float* proj_w      = (const float*)d_in[8];
  const float* proj_b      = (const float*)d_in[9];
  char* ws = (char*)d_ws;
  float* bt  = (float*)(ws + OFF_BT);
  float* rpb = (float*)(ws + OFF_RPB);
  f16* wq    = (f16*)(ws + OFF_WQKV);
  f16* wp    = (f16*)(ws + OFF_WPROJ);
  f16* qws   = (f16*)(ws + OFF_Q);
  f16* kws   = (f16*)(ws + OFF_K);
  f16* vws   = (f16*)(ws + OFF_V);
  f16* avs   = (f16*)(ws + OFF_AV);
  float* out = (float*)d_out;

  prep_bt<<<dim3(507), dim3(64), 0, stream>>>(cpb_w1, cpb_b1, cpb_w2, bt);
  prep_rpb<<<dim3(784), dim3(128), 0, stream>>>(bt, rpb);
  prep_wt<<<dim3(768), dim3(256), 0, stream>>>(qkv_w, proj_w, wq, wp);
  qkv_gemm<<<dim3(9408), dim3(256), 0, stream>>>(x, wq, q_bias, v_bias, qws, kws, vws);
  attn_kernel<<<dim3(4096), dim3(256), 0, stream>>>(qws, kws, vws, rpb, logit_scale, avs);
  proj_gemm<<<dim3(3136), dim3(256), 0, stream>>>(avs, wp, proj_b, out);
}

// Round 2
// 832.502 us; speedup vs baseline: 1.3640x; 1.3640x over previous
//
#include <hip/hip_runtime.h>
#include <math.h>

typedef _Float16 f16;
typedef _Float16 f16x8 __attribute__((ext_vector_type(8)));
typedef float f32x4 __attribute__((ext_vector_type(4)));

#define NTOK 98
#define BWIN 2048

// ---------------- workspace layout (bytes) ----------------
#define OFF_BT    0u                      // 507*8*4
#define OFF_RPB   (1u<<20)                // 8*98*98*4
#define OFF_WQKV  (2u<<20)                // 768*256*2
#define OFF_WPROJ (3u<<20)                // 256*256*2
#define OFF_Q     (4u<<20)
#define QKV_SZ    (2048u*8u*98u*32u*2u)   // 102,760,448
#define OFF_K     (OFF_Q + QKV_SZ)
#define OFF_V     (OFF_K + QKV_SZ)
#define OFF_AV    (OFF_V + QKV_SZ)        // av: 2048*98*256*2 == QKV_SZ
#define OFF_X16   OFF_AV                  // x16 aliases av: disjoint lifetimes

// async 16B global -> LDS (direct, no VGPR round-trip). LDS dest must be
// wave-uniform base; HW writes base + lane*16.
__device__ __forceinline__ void gload16(const f16* g, f16* l) {
  __builtin_amdgcn_global_load_lds(
      (const __attribute__((address_space(1))) void*)g,
      (__attribute__((address_space(3))) void*)l, 16, 0, 0);
}

// ---------------- prep: cpb MLP -> bt[507][8] ----------------
__global__ void prep_bt(const float* __restrict__ w1, const float* __restrict__ b1,
                        const float* __restrict__ w2, float* __restrict__ bt) {
  int t = blockIdx.x;            // 0..506
  int lane = threadIdx.x;        // 64
  int a = t / 169, rem = t % 169, b = rem / 13, c = rem % 13;
  float g0 = ((float)(a - 1) / 1.000001f) * 8.0f;
  float g1 = ((float)(b - 6) / 6.000001f) * 8.0f;
  float g2 = ((float)(c - 6) / 6.000001f) * 8.0f;
  float t0 = log2f(fabsf(g0) + 1.0f) / 3.0f; t0 = (g0 < 0.f) ? -t0 : t0;
  float t1 = log2f(fabsf(g1) + 1.0f) / 3.0f; t1 = (g1 < 0.f) ? -t1 : t1;
  float t2 = log2f(fabsf(g2) + 1.0f) / 3.0f; t2 = (g2 < 0.f) ? -t2 : t2;
  float part[8] = {0.f,0.f,0.f,0.f,0.f,0.f,0.f,0.f};
#pragma unroll
  for (int jj = 0; jj < 8; jj++) {
    int j = lane * 8 + jj;
    float hv = t0 * w1[j*3] + t1 * w1[j*3+1] + t2 * w1[j*3+2] + b1[j];
    hv = fmaxf(hv, 0.f);
#pragma unroll
    for (int h = 0; h < 8; h++) part[h] += hv * w2[h*512 + j];
  }
#pragma unroll
  for (int m = 1; m < 64; m <<= 1)
#pragma unroll
    for (int h = 0; h < 8; h++) part[h] += __shfl_xor(part[h], m);
  if (lane == 0)
#pragma unroll
    for (int h = 0; h < 8; h++) bt[t*8 + h] = part[h];
}

// ---------------- prep: gather + sigmoid -> rpb[8][98][98] fp32 ----------------
__global__ void prep_rpb(const float* __restrict__ bt, float* __restrict__ rpb) {
  int bid = blockIdx.x;          // 8*98
  int h = bid / 98, i = bid % 98;
  int j = threadIdx.x;
  if (j >= 98) return;
  int di = i / 49, hi = (i % 49) / 7, wi = i % 7;
  int dj = j / 49, hj = (j % 49) / 7, wj = j % 7;
  int idx = (di - dj + 1) * 169 + (hi - hj + 6) * 13 + (wi - wj + 6);
  float v = bt[idx*8 + h];
  rpb[(h*98 + i)*98 + j] = 16.0f / (1.0f + expf(-v));
}

// ---------------- prep: weights fp32 -> fp16 ----------------
__global__ void prep_wt(const float* __restrict__ qkv_w, const float* __restrict__ proj_w,
                        f16* __restrict__ wq, f16* __restrict__ wp) {
  int t = blockIdx.x * 256 + threadIdx.x;   // grid covers 768*256
  wq[t] = (f16)qkv_w[t];
  if (t < 256*256) wp[t] = (f16)proj_w[t];
}

// ---------------- prep: x fp32 -> fp16 ----------------
__global__ __launch_bounds__(256) void prep_x16(const float* __restrict__ x, f16* __restrict__ x16) {
  size_t i = ((size_t)blockIdx.x * 256 + threadIdx.x) * 8;
  float4 a = *(const float4*)(x + i);
  float4 b = *(const float4*)(x + i + 4);
  f16x8 o;
  o[0]=(f16)a.x; o[1]=(f16)a.y; o[2]=(f16)a.z; o[3]=(f16)a.w;
  o[4]=(f16)b.x; o[5]=(f16)b.y; o[6]=(f16)b.z; o[7]=(f16)b.w;
  *(f16x8*)(x16 + i) = o;
}

// ---------------- QKV GEMM: m97-style global_load_lds staging, linear LDS ----------------
// x16:[200704,256] f16, wq:[768,256] f16 -> q/k/v scatter [b][h][tok][32] f16
__global__ __launch_bounds__(256) void qkv_gemm(
    const f16* __restrict__ x16, const f16* __restrict__ wq,
    const float* __restrict__ q_bias, const float* __restrict__ v_bias,
    f16* __restrict__ qw, f16* __restrict__ kw, f16* __restrict__ vw) {
  __shared__ f16 Al[128*32];   // linear [row][32] — gload_lds dest must be linear
  __shared__ f16 Bl[128*32];
  int tid = threadIdx.x;
  int w = tid >> 6, lane = tid & 63, q4 = lane >> 4, l15 = lane & 15;

  // XCD-chunked bijective swizzle (nwg = 9408 = 8*1176), n-tile FASTEST:
  // the 6 blocks sharing an A panel run adjacently on one XCD (FETCH 303->117 MB, r1-proven).
  int bid = blockIdx.x;
  int sid = (bid & 7) * 1176 + (bid >> 3);
  int n_t = sid % 6, m_t = sid / 6;
  int m0 = m_t * 128, n0 = n_t * 128;

  f32x4 acc[2][8] = {};
  for (int ks = 0; ks < 8; ks++) {
    __syncthreads();               // previous tile's ds_reads complete
#pragma unroll
    for (int p = 0; p < 2; p++) {
      int e0 = p*256 + (w << 6);   // wave-uniform base element (16B units)
      int e  = e0 + lane;
      int r  = e >> 2, kc = e & 3; // 128 rows x 4 chunks of 8 f16
      gload16(x16 + (size_t)(m0 + r)*256 + ks*32 + kc*8, &Al[e0*8]);
      gload16(wq  + (size_t)(n0 + r)*256 + ks*32 + kc*8, &Bl[e0*8]);
    }
    __syncthreads();               // vmcnt(0) drain -> LDS tiles ready
    f16x8 af[2], bf[8];
#pragma unroll
    for (int mt = 0; mt < 2; mt++)
      af[mt] = *(const f16x8*)(&Al[(w*32 + mt*16 + l15)*32 + q4*8]);
#pragma unroll
    for (int nt = 0; nt < 8; nt++)
      bf[nt] = *(const f16x8*)(&Bl[(nt*16 + l15)*32 + q4*8]);
#pragma unroll
    for (int mt = 0; mt < 2; mt++)
#pragma unroll
      for (int nt = 0; nt < 8; nt++)
        acc[mt][nt] = __builtin_amdgcn_mfma_f32_16x16x32_f16(af[mt], bf[nt], acc[mt][nt], 0, 0, 0);
  }

  // epilogue: +bias, scatter to q/k/v [b][h][tok][d] fp16. s uniform per block.
  int s = n_t >> 1;
  f16* dst = (s == 0) ? qw : ((s == 1) ? kw : vw);
#pragma unroll
  for (int mt = 0; mt < 2; mt++)
#pragma unroll
    for (int nt = 0; nt < 8; nt++) {
      int c = n0 + nt*16 + l15;
      int hcol = (c >> 5) & 7, d = c & 31;
      float bias = (s == 0) ? q_bias[c & 255] : ((s == 2) ? v_bias[c & 255] : 0.0f);
#pragma unroll
      for (int r = 0; r < 4; r++) {
        int m = m0 + w*32 + mt*16 + q4*4 + r;
        int b = m / 98, tok = m % 98;
        dst[((size_t)(b*8 + hcol)*98 + tok)*32 + d] = (f16)(acc[mt][nt][r] + bias);
      }
    }
}

// ---------------- attention: ONE WAVE per (window, head), no barriers/atomics ----------------
#define P_STR 136
__global__ __launch_bounds__(256) void attn_kernel(
    const f16* __restrict__ qw, const f16* __restrict__ kw, const f16* __restrict__ vw,
    const float* __restrict__ rpb, const float* __restrict__ logit_scale,
    f16* __restrict__ av) {
  __shared__ f16 Ps[4*16*P_STR];   // per-wave 16x136 P bounce (C-layout -> A-layout)

  int tid = threadIdx.x;
  int wv = tid >> 6, lane = tid & 63, q4 = lane >> 4, l15 = lane & 15;
  int pair = blockIdx.x * 4 + wv;
  int b = pair >> 3, h = pair & 7;
  float scale = __expf(fminf(logit_scale[h], 4.6051701859880914f));
  const f16* qg = qw + ((size_t)pair) * (98*32);
  const f16* kg = kw + ((size_t)pair) * (98*32);
  const f16* vg = vw + ((size_t)pair) * (98*32);
  f16* pbuf = &Ps[wv * 16 * P_STR];

  // zero P cols [112,128) once (never rewritten)
  {
    int r = lane >> 2, c0 = 112 + (lane & 3) * 4;
    *(ushort4*)(&pbuf[r*P_STR + c0]) = ushort4{0,0,0,0};
  }

  // ---- K fragments, L2-normalized, resident in regs ----
  f16x8 kf[7];
#pragma unroll
  for (int nt = 0; nt < 7; nt++) {
    int row = nt*16 + l15; if (row > 97) row = 97;
    f16x8 raw = *(const f16x8*)(kg + row*32 + q4*8);
    float ss = 0.f;
#pragma unroll
    for (int j = 0; j < 8; j++) { float v = (float)raw[j]; ss = fmaf(v, v, ss); }
    ss += __shfl_xor(ss, 16);
    ss += __shfl_xor(ss, 32);
    float inv = 1.0f / fmaxf(sqrtf(ss), 1e-12f);
#pragma unroll
    for (int j = 0; j < 8; j++) kf[nt][j] = (f16)((float)raw[j] * inv);
  }

  // ---- V fragments: B-layout (needs V^T) via scalar loads, resident ----
  f16x8 vf[2][4];
#pragma unroll
  for (int n = 0; n < 2; n++)
#pragma unroll
    for (int kt = 0; kt < 4; kt++)
#pragma unroll
      for (int j = 0; j < 8; j++) {
        int tok = kt*32 + q4*8 + j; if (tok > 97) tok = 97;
        vf[n][kt][j] = vg[tok*32 + n*16 + l15];
      }

  const float* rpb_h = rpb + (size_t)h * 98 * 98;

  // ---- 7 row strips of 16 ----
  for (int mt = 0; mt < 7; mt++) {
    // Q strip fragment, normalized
    int qrow = mt*16 + l15; if (qrow > 97) qrow = 97;
    f16x8 qraw = *(const f16x8*)(qg + qrow*32 + q4*8);
    float ss = 0.f;
#pragma unroll
    for (int j = 0; j < 8; j++) { float v = (float)qraw[j]; ss = fmaf(v, v, ss); }
    ss += __shfl_xor(ss, 16);
    ss += __shfl_xor(ss, 32);
    float qinv = 1.0f / fmaxf(sqrtf(ss), 1e-12f);
    f16x8 aq;
#pragma unroll
    for (int j = 0; j < 8; j++) aq[j] = (f16)((float)qraw[j] * qinv);

    // S tiles -> logits
    f32x4 lg[7];
#pragma unroll
    for (int nt = 0; nt < 7; nt++) {
      f32x4 z = {0.f,0.f,0.f,0.f};
      lg[nt] = __builtin_amdgcn_mfma_f32_16x16x32_f16(aq, kf[nt], z, 0, 0, 0);
    }
#pragma unroll
    for (int nt = 0; nt < 7; nt++) {
      int col = nt*16 + l15;
#pragma unroll
      for (int r = 0; r < 4; r++) {
        int row = mt*16 + q4*4 + r;
        float lv = -1e30f;
        if (row < 98 && col < 98)
          lv = fmaf(scale, lg[nt][r], rpb_h[row*98 + col]);
        lg[nt][r] = lv;
      }
    }
    // row max (7 fmax + 4 shfls per r)
    float mx[4];
#pragma unroll
    for (int r = 0; r < 4; r++) {
      float m = lg[0][r];
#pragma unroll
      for (int nt = 1; nt < 7; nt++) m = fmaxf(m, lg[nt][r]);
      m = fmaxf(m, __shfl_xor(m, 1));
      m = fmaxf(m, __shfl_xor(m, 2));
      m = fmaxf(m, __shfl_xor(m, 4));
      m = fmaxf(m, __shfl_xor(m, 8));
      mx[r] = m;
    }
    // exp, row sum, write P strip (cols 98..111 become exp(-inf)=0)
    float rs[4] = {0.f,0.f,0.f,0.f};
#pragma unroll
    for (int nt = 0; nt < 7; nt++) {
      int col = nt*16 + l15;
#pragma unroll
      for (int r = 0; r < 4; r++) {
        float p = __expf(lg[nt][r] - mx[r]);
        rs[r] += p;
        pbuf[(q4*4 + r)*P_STR + col] = (f16)p;
      }
    }
    float inv[4];
#pragma unroll
    for (int r = 0; r < 4; r++) {
      float s = rs[r];
      s += __shfl_xor(s, 1);
      s += __shfl_xor(s, 2);
      s += __shfl_xor(s, 4);
      s += __shfl_xor(s, 8);
      inv[r] = 1.0f / s;
    }
    // P C-layout -> A-layout via wave-private LDS (in-order DS, no barrier)
    f16x8 pf[4];
#pragma unroll
    for (int kt = 0; kt < 4; kt++)
      pf[kt] = *(const f16x8*)(&pbuf[l15*P_STR + kt*32 + q4*8]);
    // AV
#pragma unroll
    for (int n = 0; n < 2; n++) {
      f32x4 acc = {0.f,0.f,0.f,0.f};
#pragma unroll
      for (int kt = 0; kt < 4; kt++)
        acc = __builtin_amdgcn_mfma_f32_16x16x32_f16(pf[kt], vf[n][kt], acc, 0, 0, 0);
      int d = n*16 + l15;
#pragma unroll
      for (int r = 0; r < 4; r++) {
        int row = mt*16 + q4*4 + r;
        if (row < 98)
          av[((size_t)(b*98 + row))*256 + h*32 + d] = (f16)(acc[r] * inv[r]);
      }
    }
  }
}

// ---------------- proj GEMM: [200704,256](f16) x [256,256] + bias -> fp32 out ----------------
__global__ __launch_bounds__(256) void proj_gemm(
    const f16* __restrict__ avi, const f16* __restrict__ wp,
    const float* __restrict__ pb, float* __restrict__ out) {
  __shared__ f16 Al[128*32];
  __shared__ f16 Bl[128*32];
  int tid = threadIdx.x;
  int w = tid >> 6, lane = tid & 63, q4 = lane >> 4, l15 = lane & 15;

  // XCD-chunked bijective swizzle (nwg = 3136 = 8*392), n-tile fastest
  int bid = blockIdx.x;
  int sid = (bid & 7) * 392 + (bid >> 3);
  int n_t = sid & 1, m_t = sid >> 1;
  int m0 = m_t * 128, n0 = n_t * 128;

  f32x4 acc[2][8] = {};
  for (int ks = 0; ks < 8; ks++) {
    __syncthreads();
#pragma unroll
    for (int p = 0; p < 2; p++) {
      int e0 = p*256 + (w << 6);
      int e  = e0 + lane;
      int r  = e >> 2, kc = e & 3;
      gload16(avi + (size_t)(m0 + r)*256 + ks*32 + kc*8, &Al[e0*8]);
      gload16(wp  + (size_t)(n0 + r)*256 + ks*32 + kc*8, &Bl[e0*8]);
    }
    __syncthreads();
    f16x8 af[2], bf[8];
#pragma unroll
    for (int mt = 0; mt < 2; mt++)
      af[mt] = *(const f16x8*)(&Al[(w*32 + mt*16 + l15)*32 + q4*8]);
#pragma unroll
    for (int nt = 0; nt < 8; nt++)
      bf[nt] = *(const f16x8*)(&Bl[(nt*16 + l15)*32 + q4*8]);
#pragma unroll
    for (int mt = 0; mt < 2; mt++)
#pragma unroll
      for (int nt = 0; nt < 8; nt++)
        acc[mt][nt] = __builtin_amdgcn_mfma_f32_16x16x32_f16(af[mt], bf[nt], acc[mt][nt], 0, 0, 0);
  }

#pragma unroll
  for (int mt = 0; mt < 2; mt++)
#pragma unroll
    for (int nt = 0; nt < 8; nt++) {
      int c = n0 + nt*16 + l15;
      float bias = pb[c];
#pragma unroll
      for (int r = 0; r < 4; r++) {
        int m = m0 + w*32 + mt*16 + q4*4 + r;
        out[(size_t)m*256 + c] = acc[mt][nt][r] + bias;
      }
    }
}

extern "C" void kernel_launch(void* const* d_in, const int* in_sizes, int n_in,
                              void* d_out, int out_size, void* d_ws, size_t ws_size,
                              hipStream_t stream) {
  const float* x           = (const float*)d_in[0];
  const float* qkv_w       = (const float*)d_in[1];
  const float* q_bias      = (const float*)d_in[2];
  const float* v_bias      = (const float*)d_in[3];
  const float* logit_scale = (const float*)d_in[4];
  const float* cpb_w1      = (const float*)d_in[5];
  const float* cpb_b1      = (const float*)d_in[6];
  const float* cpb_w2      = (const float*)d_in[7];
  const float* proj_w      = (const float*)d_in[8];
  const float* proj_b      = (const float*)d_in[9];
  char* ws = (char*)d_ws;
  float* bt  = (float*)(ws + OFF_BT);
  float* rpb = (float*)(ws + OFF_RPB);
  f16* wq    = (f16*)(ws + OFF_WQKV);
  f16* wp    = (f16*)(ws + OFF_WPROJ);
  f16* qws   = (f16*)(ws + OFF_Q);
  f16* kws   = (f16*)(ws + OFF_K);
  f16* vws   = (f16*)(ws + OFF_V);
  f16* avs   = (f16*)(ws + OFF_AV);
  f16* x16   = (f16*)(ws + OFF_X16);   // aliases avs; x16 dead before attn writes avs
  float* out = (float*)d_out;

  prep_bt<<<dim3(507), dim3(64), 0, stream>>>(cpb_w1, cpb_b1, cpb_w2, bt);
  prep_rpb<<<dim3(784), dim3(128), 0, stream>>>(bt, rpb);
  prep_wt<<<dim3(768), dim3(256), 0, stream>>>(qkv_w, proj_w, wq, wp);
  prep_x16<<<dim3(25088), dim3(256), 0, stream>>>(x, x16);
  qkv_gemm<<<dim3(9408), dim3(256), 0, stream>>>(x16, wq, q_bias, v_bias, qws, kws, vws);
  attn_kernel<<<dim3(4096), dim3(256), 0, stream>>>(qws, kws, vws, rpb, logit_scale, avs);
  proj_gemm<<<dim3(3136), dim3(256), 0, stream>>>(avs, wp, proj_b, out);
}

// Round 3
// 778.438 us; speedup vs baseline: 1.4587x; 1.0695x over previous
//
#include <hip/hip_runtime.h>
#include <math.h>

typedef _Float16 f16;
typedef _Float16 f16x4 __attribute__((ext_vector_type(4)));
typedef _Float16 f16x8 __attribute__((ext_vector_type(8)));
typedef float f32x4 __attribute__((ext_vector_type(4)));

#define NTOK 98
#define BWIN 2048

// ---------------- workspace layout (bytes) ----------------
#define OFF_BT    0u                      // 507*8*4
#define OFF_RPB   (1u<<20)                // 8*98*112*4 (padded stride 112)
#define OFF_WQKV  (2u<<20)                // 768*256*2
#define OFF_WPROJ (3u<<20)                // 256*256*2
#define OFF_Q     (4u<<20)
#define QKV_SZ    (2048u*8u*98u*32u*2u)   // 102,760,448
#define OFF_K     (OFF_Q + QKV_SZ)
#define OFF_V     (OFF_K + QKV_SZ)
#define OFF_AV    (OFF_V + QKV_SZ)        // av: 2048*98*256*2 == QKV_SZ

// async 16B global -> LDS (direct, no VGPR round-trip). LDS dest is
// wave-uniform base; HW writes base + lane*16.
__device__ __forceinline__ void gload16(const f16* g, f16* l) {
  __builtin_amdgcn_global_load_lds(
      (const __attribute__((address_space(1))) void*)g,
      (__attribute__((address_space(3))) void*)l, 16, 0, 0);
}
__device__ __forceinline__ void gload16f(const float* g, float* l) {
  __builtin_amdgcn_global_load_lds(
      (const __attribute__((address_space(1))) void*)g,
      (__attribute__((address_space(3))) void*)l, 16, 0, 0);
}

// ---------------- prep: cpb MLP -> bt[507][8] ----------------
__global__ void prep_bt(const float* __restrict__ w1, const float* __restrict__ b1,
                        const float* __restrict__ w2, float* __restrict__ bt) {
  int t = blockIdx.x;            // 0..506
  int lane = threadIdx.x;        // 64
  int a = t / 169, rem = t % 169, b = rem / 13, c = rem % 13;
  float g0 = ((float)(a - 1) / 1.000001f) * 8.0f;
  float g1 = ((float)(b - 6) / 6.000001f) * 8.0f;
  float g2 = ((float)(c - 6) / 6.000001f) * 8.0f;
  float t0 = log2f(fabsf(g0) + 1.0f) / 3.0f; t0 = (g0 < 0.f) ? -t0 : t0;
  float t1 = log2f(fabsf(g1) + 1.0f) / 3.0f; t1 = (g1 < 0.f) ? -t1 : t1;
  float t2 = log2f(fabsf(g2) + 1.0f) / 3.0f; t2 = (g2 < 0.f) ? -t2 : t2;
  float part[8] = {0.f,0.f,0.f,0.f,0.f,0.f,0.f,0.f};
#pragma unroll
  for (int jj = 0; jj < 8; jj++) {
    int j = lane * 8 + jj;
    float hv = t0 * w1[j*3] + t1 * w1[j*3+1] + t2 * w1[j*3+2] + b1[j];
    hv = fmaxf(hv, 0.f);
#pragma unroll
    for (int h = 0; h < 8; h++) part[h] += hv * w2[h*512 + j];
  }
#pragma unroll
  for (int m = 1; m < 64; m <<= 1)
#pragma unroll
    for (int h = 0; h < 8; h++) part[h] += __shfl_xor(part[h], m);
  if (lane == 0)
#pragma unroll
    for (int h = 0; h < 8; h++) bt[t*8 + h] = part[h];
}

// ---------------- prep: gather + sigmoid -> rpb[8][98][112] fp32 (padded) ----------------
__global__ void prep_rpb(const float* __restrict__ bt, float* __restrict__ rpb) {
  int bid = blockIdx.x;          // 8*98
  int h = bid / 98, i = bid % 98;
  int j = threadIdx.x;
  if (j >= 112) return;
  float v = 0.f;
  if (j < 98) {
    int di = i / 49, hi = (i % 49) / 7, wi = i % 7;
    int dj = j / 49, hj = (j % 49) / 7, wj = j % 7;
    int idx = (di - dj + 1) * 169 + (hi - hj + 6) * 13 + (wi - wj + 6);
    float t = bt[idx*8 + h];
    v = 16.0f / (1.0f + expf(-t));
  }
  rpb[(h*98 + i)*112 + j] = v;
}

// ---------------- prep: weights fp32 -> fp16 ----------------
__global__ void prep_wt(const float* __restrict__ qkv_w, const float* __restrict__ proj_w,
                        f16* __restrict__ wq, f16* __restrict__ wp) {
  int t = blockIdx.x * 256 + threadIdx.x;   // grid covers 768*256
  wq[t] = (f16)qkv_w[t];
  if (t < 256*256) wp[t] = (f16)proj_w[t];
}

// ---------------- QKV GEMM: fp32 A direct via global_load_lds (swizzled), f16 B ----------------
// x:[200704,256] fp32, wq:[768,256] f16 -> q/k/v scatter [b][h][tok][32] f16
__global__ __launch_bounds__(256) void qkv_gemm(
    const float* __restrict__ x, const f16* __restrict__ wq,
    const float* __restrict__ q_bias, const float* __restrict__ v_bias,
    f16* __restrict__ qw, f16* __restrict__ kw, f16* __restrict__ vw) {
  __shared__ float Alf[128*32];  // 16KB, linear dest; source XOR-swizzled at 32B granule
  __shared__ f16 Bl[128*32];     // 8KB
  int tid = threadIdx.x;
  int w = tid >> 6, lane = tid & 63, q4 = lane >> 4, l15 = lane & 15;

  // XCD-chunked bijective swizzle (nwg = 9408 = 8*1176), n-tile FASTEST:
  // the 6 blocks sharing an A panel run adjacently on one XCD (r1/r2-proven).
  int bid = blockIdx.x;
  int sid = (bid & 7) * 1176 + (bid >> 3);
  int n_t = sid % 6, m_t = sid / 6;
  int m0 = m_t * 128, n0 = n_t * 128;

  f32x4 acc[2][8] = {};
  for (int ks = 0; ks < 8; ks++) {
    __syncthreads();               // previous tile's ds_reads complete
    // A: 128 rows x 8 chunks of 4 fp32; source chunk XOR'd by ((row&3)<<1)
    // so the LDS read (b128 = 2 chunks) lands 4-way instead of 16-way banked.
#pragma unroll
    for (int p = 0; p < 4; p++) {
      int e0 = p*256 + (w << 6);   // wave-uniform chunk base
      int e  = e0 + lane;
      int r  = e >> 3, kc = e & 7;
      int kc2 = kc ^ ((r & 3) << 1);
      gload16f(x + (size_t)(m0 + r)*256 + ks*32 + kc2*4, &Alf[e0*4]);
    }
#pragma unroll
    for (int p = 0; p < 2; p++) {
      int e0 = p*256 + (w << 6);
      int e  = e0 + lane;
      int r  = e >> 2, kc = e & 3;
      gload16(wq + (size_t)(n0 + r)*256 + ks*32 + kc*8, &Bl[e0*8]);
    }
    __syncthreads();               // vmcnt(0) drain -> LDS tiles ready
    f16x8 af[2], bf[8];
#pragma unroll
    for (int mt = 0; mt < 2; mt++) {
      int row = w*32 + mt*16 + l15;
      int co = ((q4 ^ (row & 3)) << 3);   // same XOR as source
      f32x4 a0 = *(const f32x4*)(&Alf[row*32 + co]);
      f32x4 a1 = *(const f32x4*)(&Alf[row*32 + co + 4]);
      f16x8 v;
      v[0]=(f16)a0[0]; v[1]=(f16)a0[1]; v[2]=(f16)a0[2]; v[3]=(f16)a0[3];
      v[4]=(f16)a1[0]; v[5]=(f16)a1[1]; v[6]=(f16)a1[2]; v[7]=(f16)a1[3];
      af[mt] = v;
    }
#pragma unroll
    for (int nt = 0; nt < 8; nt++)
      bf[nt] = *(const f16x8*)(&Bl[(nt*16 + l15)*32 + q4*8]);
#pragma unroll
    for (int mt = 0; mt < 2; mt++)
#pragma unroll
      for (int nt = 0; nt < 8; nt++)
        acc[mt][nt] = __builtin_amdgcn_mfma_f32_16x16x32_f16(af[mt], bf[nt], acc[mt][nt], 0, 0, 0);
  }

  // epilogue: +bias, scatter to q/k/v [b][h][tok][d] fp16. s uniform per block.
  int s = n_t >> 1;
  f16* dst = (s == 0) ? qw : ((s == 1) ? kw : vw);
#pragma unroll
  for (int mt = 0; mt < 2; mt++)
#pragma unroll
    for (int nt = 0; nt < 8; nt++) {
      int c = n0 + nt*16 + l15;
      int hcol = (c >> 5) & 7, d = c & 31;
      float bias = (s == 0) ? q_bias[c & 255] : ((s == 2) ? v_bias[c & 255] : 0.0f);
#pragma unroll
      for (int r = 0; r < 4; r++) {
        int m = m0 + w*32 + mt*16 + q4*4 + r;
        int b = m / 98, tok = m % 98;
        dst[((size_t)(b*8 + hcol)*98 + tok)*32 + d] = (f16)(acc[mt][nt][r] + bias);
      }
    }
}

// ---------------- attention: ONE WAVE per (window, head), swapped QK^T ----------------
// S^T = mfma(K, Q): each lane owns ONE q-row (l15) -> softmax reduce = 2 shfls,
// rpb = float4 loads, P write = ds_write_b64, 1/sum folded into P.
#define P_STR 136
__global__ __launch_bounds__(256) void attn_kernel(
    const f16* __restrict__ qw, const f16* __restrict__ kw, const f16* __restrict__ vw,
    const float* __restrict__ rpb, const float* __restrict__ logit_scale,
    f16* __restrict__ av) {
  __shared__ f16 Ps[4*16*P_STR];   // per-wave 16x136 P bounce

  int tid = threadIdx.x;
  int wv = tid >> 6, lane = tid & 63, q4 = lane >> 4, l15 = lane & 15;
  int pair = blockIdx.x * 4 + wv;
  int b = pair >> 3, h = pair & 7;
  float scale = __expf(fminf(logit_scale[h], 4.6051701859880914f));
  const f16* qg = qw + ((size_t)pair) * (98*32);
  const f16* kg = kw + ((size_t)pair) * (98*32);
  const f16* vg = vw + ((size_t)pair) * (98*32);
  f16* pbuf = &Ps[wv * 16 * P_STR];

  // zero P cols [112,128) once (never rewritten)
  {
    int r = lane >> 2, c0 = 112 + (lane & 3) * 4;
    *(ushort4*)(&pbuf[r*P_STR + c0]) = ushort4{0,0,0,0};
  }

  // ---- K fragments (A-operand; same lane mapping), L2-normalized, resident ----
  f16x8 kf[7];
#pragma unroll
  for (int nt = 0; nt < 7; nt++) {
    int row = nt*16 + l15; if (row > 97) row = 97;
    f16x8 raw = *(const f16x8*)(kg + row*32 + q4*8);
    float ss = 0.f;
#pragma unroll
    for (int j = 0; j < 8; j++) { float v = (float)raw[j]; ss = fmaf(v, v, ss); }
    ss += __shfl_xor(ss, 16);
    ss += __shfl_xor(ss, 32);
    float inv = 1.0f / fmaxf(sqrtf(ss), 1e-12f);
#pragma unroll
    for (int j = 0; j < 8; j++) kf[nt][j] = (f16)((float)raw[j] * inv);
  }

  // ---- V fragments: B-layout via scalar loads, resident ----
  f16x8 vf[2][4];
#pragma unroll
  for (int n = 0; n < 2; n++)
#pragma unroll
    for (int kt = 0; kt < 4; kt++)
#pragma unroll
      for (int j = 0; j < 8; j++) {
        int tok = kt*32 + q4*8 + j; if (tok > 97) tok = 97;
        vf[n][kt][j] = vg[tok*32 + n*16 + l15];
      }

  const float* rpb_h = rpb + (size_t)h * 98 * 112;

  // ---- 7 row strips of 16 q-rows ----
  for (int mt = 0; mt < 7; mt++) {
    int qrow = mt*16 + l15;              // this lane's q-row (B-operand col)
    int qcl = (qrow > 97) ? 97 : qrow;
    bool qv = qrow < 98;
    f16x8 qraw = *(const f16x8*)(qg + qcl*32 + q4*8);
    float ss = 0.f;
#pragma unroll
    for (int j = 0; j < 8; j++) { float v = (float)qraw[j]; ss = fmaf(v, v, ss); }
    ss += __shfl_xor(ss, 16);
    ss += __shfl_xor(ss, 32);
    float qinv = 1.0f / fmaxf(sqrtf(ss), 1e-12f);
    f16x8 aq;
#pragma unroll
    for (int j = 0; j < 8; j++) aq[j] = (f16)((float)qraw[j] * qinv);

    // S^T tiles: lg[nt][r] = dot(Q[qrow], K[nt*16 + q4*4 + r])
    f32x4 lg[7];
    __builtin_amdgcn_s_setprio(1);
#pragma unroll
    for (int nt = 0; nt < 7; nt++) {
      f32x4 z = {0.f,0.f,0.f,0.f};
      lg[nt] = __builtin_amdgcn_mfma_f32_16x16x32_f16(kf[nt], aq, z, 0, 0, 0);
    }
    __builtin_amdgcn_s_setprio(0);

    // logits + rpb (float4: 4 consecutive k), lane-local row max
    float mrow = -1e30f;
#pragma unroll
    for (int nt = 0; nt < 7; nt++) {
      float4 rp = *(const float4*)(rpb_h + (size_t)qcl*112 + nt*16 + q4*4);
#pragma unroll
      for (int r = 0; r < 4; r++) {
        int k = nt*16 + q4*4 + r;
        float rv = (r == 0) ? rp.x : (r == 1) ? rp.y : (r == 2) ? rp.z : rp.w;
        float lv = (qv && k < 98) ? fmaf(scale, lg[nt][r], rv) : -1e30f;
        lg[nt][r] = lv;
        mrow = fmaxf(mrow, lv);
      }
    }
    mrow = fmaxf(mrow, __shfl_xor(mrow, 16));
    mrow = fmaxf(mrow, __shfl_xor(mrow, 32));
    // exp + lane-local sum
    float s = 0.f;
#pragma unroll
    for (int nt = 0; nt < 7; nt++)
#pragma unroll
      for (int r = 0; r < 4; r++) {
        float p = __expf(lg[nt][r] - mrow);
        lg[nt][r] = p;
        s += p;
      }
    s += __shfl_xor(s, 16);
    s += __shfl_xor(s, 32);
    float inv = 1.0f / s;
    // write P rows [q-local = l15][k], normalized, 4 consecutive k per ds_write_b64
#pragma unroll
    for (int nt = 0; nt < 7; nt++) {
      f16x4 pv;
#pragma unroll
      for (int r = 0; r < 4; r++) pv[r] = (f16)(lg[nt][r] * inv);
      *(f16x4*)(&pbuf[l15*P_STR + nt*16 + q4*4]) = pv;
    }
    // read A-frags (in-order DS within wave, no barrier)
    f16x8 pf[4];
#pragma unroll
    for (int kt = 0; kt < 4; kt++)
      pf[kt] = *(const f16x8*)(&pbuf[l15*P_STR + kt*32 + q4*8]);
    // AV (P already normalized)
    __builtin_amdgcn_s_setprio(1);
    f32x4 oacc[2];
#pragma unroll
    for (int n = 0; n < 2; n++) {
      f32x4 acc = {0.f,0.f,0.f,0.f};
#pragma unroll
      for (int kt = 0; kt < 4; kt++)
        acc = __builtin_amdgcn_mfma_f32_16x16x32_f16(pf[kt], vf[n][kt], acc, 0, 0, 0);
      oacc[n] = acc;
    }
    __builtin_amdgcn_s_setprio(0);
#pragma unroll
    for (int n = 0; n < 2; n++) {
      int d = n*16 + l15;
#pragma unroll
      for (int r = 0; r < 4; r++) {
        int row = mt*16 + q4*4 + r;
        if (row < 98)
          av[((size_t)(b*98 + row))*256 + h*32 + d] = (f16)oacc[n][r];
      }
    }
  }
}

// ---------------- proj GEMM: [200704,256](f16) x [256,256] + bias -> fp32 out ----------------
__global__ __launch_bounds__(256) void proj_gemm(
    const f16* __restrict__ avi, const f16* __restrict__ wp,
    const float* __restrict__ pb, float* __restrict__ out) {
  __shared__ f16 Al[128*32];
  __shared__ f16 Bl[128*32];
  int tid = threadIdx.x;
  int w = tid >> 6, lane = tid & 63, q4 = lane >> 4, l15 = lane & 15;

  // XCD-chunked bijective swizzle (nwg = 3136 = 8*392), n-tile fastest
  int bid = blockIdx.x;
  int sid = (bid & 7) * 392 + (bid >> 3);
  int n_t = sid & 1, m_t = sid >> 1;
  int m0 = m_t * 128, n0 = n_t * 128;

  f32x4 acc[2][8] = {};
  for (int ks = 0; ks < 8; ks++) {
    __syncthreads();
#pragma unroll
    for (int p = 0; p < 2; p++) {
      int e0 = p*256 + (w << 6);
      int e  = e0 + lane;
      int r  = e >> 2, kc = e & 3;
      gload16(avi + (size_t)(m0 + r)*256 + ks*32 + kc*8, &Al[e0*8]);
      gload16(wp  + (size_t)(n0 + r)*256 + ks*32 + kc*8, &Bl[e0*8]);
    }
    __syncthreads();
    f16x8 af[2], bf[8];
#pragma unroll
    for (int mt = 0; mt < 2; mt++)
      af[mt] = *(const f16x8*)(&Al[(w*32 + mt*16 + l15)*32 + q4*8]);
#pragma unroll
    for (int nt = 0; nt < 8; nt++)
      bf[nt] = *(const f16x8*)(&Bl[(nt*16 + l15)*32 + q4*8]);
#pragma unroll
    for (int mt = 0; mt < 2; mt++)
#pragma unroll
      for (int nt = 0; nt < 8; nt++)
        acc[mt][nt] = __builtin_amdgcn_mfma_f32_16x16x32_f16(af[mt], bf[nt], acc[mt][nt], 0, 0, 0);
  }

#pragma unroll
  for (int mt = 0; mt < 2; mt++)
#pragma unroll
    for (int nt = 0; nt < 8; nt++) {
      int c = n0 + nt*16 + l15;
      float bias = pb[c];
#pragma unroll
      for (int r = 0; r < 4; r++) {
        int m = m0 + w*32 + mt*16 + q4*4 + r;
        out[(size_t)m*256 + c] = acc[mt][nt][r] + bias;
      }
    }
}

extern "C" void kernel_launch(void* const* d_in, const int* in_sizes, int n_in,
                              void* d_out, int out_size, void* d_ws, size_t ws_size,
                              hipStream_t stream) {
  const float* x           = (const float*)d_in[0];
  const float* qkv_w       = (const float*)d_in[1];
  const float* q_bias      = (const float*)d_in[2];
  const float* v_bias      = (const float*)d_in[3];
  const float* logit_scale = (const float*)d_in[4];
  const float* cpb_w1      = (const float*)d_in[5];
  const float* cpb_b1      = (const float*)d_in[6];
  const float* cpb_w2      = (const float*)d_in[7];
  const float* proj_w      = (const float*)d_in[8];
  const float* proj_b      = (const float*)d_in[9];
  char* ws = (char*)d_ws;
  float* bt  = (float*)(ws + OFF_BT);
  float* rpb = (float*)(ws + OFF_RPB);
  f16* wq    = (f16*)(ws + OFF_WQKV);
  f16* wp    = (f16*)(ws + OFF_WPROJ);
  f16* qws   = (f16*)(ws + OFF_Q);
  f16* kws   = (f16*)(ws + OFF_K);
  f16* vws   = (f16*)(ws + OFF_V);
  f16* avs   = (f16*)(ws + OFF_AV);
  float* out = (float*)d_out;

  prep_bt<<<dim3(507), dim3(64), 0, stream>>>(cpb_w1, cpb_b1, cpb_w2, bt);
  prep_rpb<<<dim3(784), dim3(128), 0, stream>>>(bt, rpb);
  prep_wt<<<dim3(768), dim3(256), 0, stream>>>(qkv_w, proj_w, wq, wp);
  qkv_gemm<<<dim3(9408), dim3(256), 0, stream>>>(x, wq, q_bias, v_bias, qws, kws, vws);
  attn_kernel<<<dim3(4096), dim3(256), 0, stream>>>(qws, kws, vws, rpb, logit_scale, avs);
  proj_gemm<<<dim3(3136), dim3(256), 0, stream>>>(avs, wp, proj_b, out);
}